// Round 6
// baseline (162.011 us; speedup 1.0000x reference)
//
#include <hip/hip_runtime.h>

// Per-edge cosine similarity, int8-quantized normalized rows (128 B/row = 1 line).
// Round 6: max out outstanding-miss ILP — 4 edges per 8-lane group (8 independent
// row-line loads issued before any use) + 512-thread blocks for occupancy.
// Edge gather is at its structural floor: 2 random lines/edge, int8 precision floor.

#define FD 64

__device__ __forceinline__ int q8pack(float v0, float v1, float v2, float v3, float inv) {
    float a0 = fminf(fmaxf(v0 * inv, -127.f), 127.f);
    float a1 = fminf(fmaxf(v1 * inv, -127.f), 127.f);
    float a2 = fminf(fmaxf(v2 * inv, -127.f), 127.f);
    float a3 = fminf(fmaxf(v3 * inv, -127.f), 127.f);
    int q0 = ((int)rintf(a0)) & 0xff;
    int q1 = ((int)rintf(a1)) & 0xff;
    int q2 = ((int)rintf(a2)) & 0xff;
    int q3 = ((int)rintf(a3)) & 0xff;
    return q0 | (q1 << 8) | (q2 << 16) | (q3 << 24);
}

__global__ void pack_kernel(const float4* __restrict__ xd, const float4* __restrict__ hd,
                            const float4* __restrict__ xg, const float4* __restrict__ hg,
                            int2* __restrict__ fd, int2* __restrict__ fg,
                            float* __restrict__ sd, float* __restrict__ sg,
                            int n_d, int n_g)
{
    int tid  = (int)(blockIdx.x * blockDim.x + threadIdx.x);
    int node = tid >> 4;
    int lane = threadIdx.x & 15;
    int total = n_d + n_g;
    if (node >= total) return;

    const float4* x; const float4* h; int2* o; float* s; int n;
    if (node < n_d) { x = xd; h = hd; o = fd; s = sd; n = node; }
    else            { x = xg; h = hg; o = fg; s = sg; n = node - n_d; }

    float4 a = x[(size_t)n * 16 + lane];
    float4 b = h[(size_t)n * 16 + lane];

    float ss = a.x*a.x + a.y*a.y + a.z*a.z + a.w*a.w
             + b.x*b.x + b.y*b.y + b.z*b.z + b.w*b.w;
    #pragma unroll
    for (int m = 8; m >= 1; m >>= 1) ss += __shfl_xor(ss, m);
    float r = rsqrtf(ss);

    a.x *= r; a.y *= r; a.z *= r; a.w *= r;
    b.x *= r; b.y *= r; b.z *= r; b.w *= r;

    float mx = fmaxf(fmaxf(fmaxf(fabsf(a.x), fabsf(a.y)), fmaxf(fabsf(a.z), fabsf(a.w))),
                     fmaxf(fmaxf(fabsf(b.x), fabsf(b.y)), fmaxf(fabsf(b.z), fabsf(b.w))));
    #pragma unroll
    for (int m = 8; m >= 1; m >>= 1) mx = fmaxf(mx, __shfl_xor(mx, m));

    float inv = 127.0f / mx;

    int2 w;
    w.x = q8pack(a.x, a.y, a.z, a.w, inv);
    w.y = q8pack(b.x, b.y, b.z, b.w, inv);
    o[(size_t)n * 16 + lane] = w;

    if (lane == 0) s[n] = mx * (1.0f / 127.0f);
}

__device__ __forceinline__ int dot4(int a, int b, int c) {
    return __builtin_amdgcn_sdot4(a, b, c, false);   // v_dot4_i32_i8
}

// 8 lanes per group, 4 edges per group: 8 independent row-line loads in flight.
__global__ __launch_bounds__(512, 4)
void edge_kernel4(const int4* __restrict__ fd, const int4* __restrict__ fg,
                  const float* __restrict__ sd, const float* __restrict__ sg,
                  const int* __restrict__ src, const int* __restrict__ dst,
                  float* __restrict__ out, int n_edges)
{
    int tid  = (int)(blockIdx.x * blockDim.x + threadIdx.x);
    int lane = threadIdx.x & 7;
    int g    = tid >> 3;
    int e0   = g * 4;
    if (e0 >= n_edges) return;

    int rem = n_edges - e0;                 // >=1
    int e1 = e0 + min(1, rem - 1);
    int e2 = e0 + min(2, rem - 1);
    int e3 = e0 + min(3, rem - 1);

    int s0 = src[e0], d0 = dst[e0];
    int s1 = src[e1], d1 = dst[e1];
    int s2 = src[e2], d2 = dst[e2];
    int s3 = src[e3], d3 = dst[e3];

    int4 a0 = fd[(size_t)s0 * 8 + lane];
    int4 b0 = fg[(size_t)d0 * 8 + lane];
    int4 a1 = fd[(size_t)s1 * 8 + lane];
    int4 b1 = fg[(size_t)d1 * 8 + lane];
    int4 a2 = fd[(size_t)s2 * 8 + lane];
    int4 b2 = fg[(size_t)d2 * 8 + lane];
    int4 a3 = fd[(size_t)s3 * 8 + lane];
    int4 b3 = fg[(size_t)d3 * 8 + lane];

    int acc0 = dot4(a0.x, b0.x, dot4(a0.y, b0.y, dot4(a0.z, b0.z, dot4(a0.w, b0.w, 0))));
    int acc1 = dot4(a1.x, b1.x, dot4(a1.y, b1.y, dot4(a1.z, b1.z, dot4(a1.w, b1.w, 0))));
    int acc2 = dot4(a2.x, b2.x, dot4(a2.y, b2.y, dot4(a2.z, b2.z, dot4(a2.w, b2.w, 0))));
    int acc3 = dot4(a3.x, b3.x, dot4(a3.y, b3.y, dot4(a3.z, b3.z, dot4(a3.w, b3.w, 0))));

    #pragma unroll
    for (int m = 4; m >= 1; m >>= 1) {
        acc0 += __shfl_xor(acc0, m);
        acc1 += __shfl_xor(acc1, m);
        acc2 += __shfl_xor(acc2, m);
        acc3 += __shfl_xor(acc3, m);
    }

    if (lane == 0) {
        out[e0] = (float)acc0 * sd[s0] * sg[d0];
        if (rem > 1) out[e1] = (float)acc1 * sd[s1] * sg[d1];
        if (rem > 2) out[e2] = (float)acc2 * sd[s2] * sg[d2];
        if (rem > 3) out[e3] = (float)acc3 * sd[s3] * sg[d3];
    }
}

extern "C" void kernel_launch(void* const* d_in, const int* in_sizes, int n_in,
                              void* d_out, int out_size, void* d_ws, size_t ws_size,
                              hipStream_t stream) {
    const float* xd = (const float*)d_in[0];
    const float* hd = (const float*)d_in[1];
    const float* xg = (const float*)d_in[2];
    const float* hg = (const float*)d_in[3];
    const int*  src = (const int*)d_in[4];
    const int*  dst = (const int*)d_in[5];

    int n_d     = in_sizes[0] / FD;
    int n_g     = in_sizes[2] / FD;
    int n_edges = in_sizes[4];

    // ws layout: fd rows (n_d*128 B) | fg rows (n_g*128 B) | sd | sg
    char* ws = (char*)d_ws;
    int2*  fd = (int2*)ws;   ws += (size_t)n_d * 128;
    int2*  fg = (int2*)ws;   ws += (size_t)n_g * 128;
    float* sd = (float*)ws;  ws += (size_t)n_d * sizeof(float);
    float* sg = (float*)ws;
    float* out = (float*)d_out;

    int total_nodes = n_d + n_g;
    int nb1 = (total_nodes * 16 + 255) / 256;
    pack_kernel<<<nb1, 256, 0, stream>>>((const float4*)xd, (const float4*)hd,
                                         (const float4*)xg, (const float4*)hg,
                                         fd, fg, sd, sg, n_d, n_g);

    long long groups = ((long long)n_edges + 3) / 4;
    int nb2 = (int)((groups * 8 + 511) / 512);
    edge_kernel4<<<nb2, 512, 0, stream>>>((const int4*)fd, (const int4*)fg,
                                          sd, sg, src, dst, out, n_edges);
}